// Round 1
// baseline (333.777 us; speedup 1.0000x reference)
//
#include <hip/hip_runtime.h>
#include <hip/hip_bf16.h>
#include <cstdint>

// Problem dims (fixed by reference): n=8, c=128, HW=192*192=36864, Q=128.
// This is attention: queries = K[n] (128x128), keys/values = x[n] columns.
// Kernel 1 (flash_partial): split-S online-softmax partials.
// Kernel 2 (combine): merge partials across s-chunks.

#define TS 32
#define XPAD 132   // 16B-aligned row stride for x tile
#define WPAD 132

__global__ __launch_bounds__(256, 2)
void flash_partial(const float* __restrict__ xg, const float* __restrict__ Kg,
                   float* __restrict__ wsm, float* __restrict__ wsl,
                   float* __restrict__ wacc, int SC, int sPerBlock)
{
    __shared__ __align__(16) float xt[TS][XPAD];   // x tile, [s][c]
    __shared__ __align__(16) float wt[TS][WPAD];   // weights tile, [s][q]
    __shared__ float m_l[128], l_l[128], r_l[128], tm_l[128], ts_l[128];

    const int tid   = threadIdx.x;
    const int scIdx = blockIdx.x;
    const int n     = blockIdx.y;

    if (tid < 128) { m_l[tid] = -INFINITY; l_l[tid] = 0.f; }

    // phase-B (scores) mapping: this thread owns s in {sb, sb+8, sb+16, sb+24}, q in [qb, qb+4)
    const int sb = tid & 7;
    const int qb = (tid >> 3) * 4;
    // phase-C (PV accum) mapping: this thread owns q in [q2,q2+8), c in [c2,c2+8)
    const int q2 = (tid >> 4) * 8;
    const int c2 = (tid & 15) * 8;

    const float* kbase = Kg + ((size_t)n * 128 + qb) * 128;

    float acc[8][8];
    #pragma unroll
    for (int j = 0; j < 8; ++j)
        #pragma unroll
        for (int k = 0; k < 8; ++k) acc[j][k] = 0.f;

    int s0 = scIdx * sPerBlock;
    const int nTiles = sPerBlock >> 5;

    for (int tile = 0; tile < nTiles; ++tile, s0 += TS) {
        __syncthreads();   // xt/wt safe to overwrite; also covers m_l/l_l init

        // ---- A: load x tile, transpose into LDS [s][c] ----
        {
            const int c_ = tid >> 3;
            const int s4 = (tid & 7) << 2;
            #pragma unroll
            for (int p = 0; p < 4; ++p) {
                const int c = (p << 5) + c_;
                float4 v = *reinterpret_cast<const float4*>(
                    xg + ((size_t)n * 128 + c) * 36864 + s0 + s4);
                xt[s4 + 0][c] = v.x;
                xt[s4 + 1][c] = v.y;
                xt[s4 + 2][c] = v.z;
                xt[s4 + 3][c] = v.w;
            }
        }
        __syncthreads();

        // ---- B1: scores[s][q] = sum_c x[s][c] * K[q][c] ----
        float scf[4][4];
        #pragma unroll
        for (int i = 0; i < 4; ++i)
            #pragma unroll
            for (int j = 0; j < 4; ++j) scf[i][j] = 0.f;
        {
            const float4* xr0 = reinterpret_cast<const float4*>(&xt[sb][0]);
            const float4* xr1 = reinterpret_cast<const float4*>(&xt[sb + 8][0]);
            const float4* xr2 = reinterpret_cast<const float4*>(&xt[sb + 16][0]);
            const float4* xr3 = reinterpret_cast<const float4*>(&xt[sb + 24][0]);
            const float4* k0 = reinterpret_cast<const float4*>(kbase);
            const float4* k1 = reinterpret_cast<const float4*>(kbase + 128);
            const float4* k2 = reinterpret_cast<const float4*>(kbase + 256);
            const float4* k3 = reinterpret_cast<const float4*>(kbase + 384);
            #pragma unroll 4
            for (int c4 = 0; c4 < 32; ++c4) {
                float4 xv[4] = { xr0[c4], xr1[c4], xr2[c4], xr3[c4] };
                float4 kv[4] = { k0[c4],  k1[c4],  k2[c4],  k3[c4]  };
                #pragma unroll
                for (int i = 0; i < 4; ++i)
                    #pragma unroll
                    for (int j = 0; j < 4; ++j) {
                        scf[i][j] = fmaf(xv[i].x, kv[j].x, scf[i][j]);
                        scf[i][j] = fmaf(xv[i].y, kv[j].y, scf[i][j]);
                        scf[i][j] = fmaf(xv[i].z, kv[j].z, scf[i][j]);
                        scf[i][j] = fmaf(xv[i].w, kv[j].w, scf[i][j]);
                    }
            }
        }

        // ---- B2: per-q tile max (reduce over 8 lanes owning this q) ----
        #pragma unroll
        for (int j = 0; j < 4; ++j) {
            float tm = fmaxf(fmaxf(scf[0][j], scf[1][j]), fmaxf(scf[2][j], scf[3][j]));
            tm = fmaxf(tm, __shfl_xor(tm, 1));
            tm = fmaxf(tm, __shfl_xor(tm, 2));
            tm = fmaxf(tm, __shfl_xor(tm, 4));
            if (sb == 0) tm_l[qb + j] = tm;
        }
        __syncthreads();

        // ---- B3: online-softmax stats update ----
        if (tid < 128) {
            const float mo = m_l[tid];
            const float mn = fmaxf(mo, tm_l[tid]);
            r_l[tid] = __expf(mo - mn);   // 0 on first tile (mo = -inf)
            m_l[tid] = mn;
        }
        __syncthreads();

        // ---- B4: weights w = exp(s - m_new) -> LDS, plus row sums ----
        #pragma unroll
        for (int j = 0; j < 4; ++j) {
            const float mq = m_l[qb + j];
            float rs = 0.f;
            #pragma unroll
            for (int i = 0; i < 4; ++i) {
                const float w = __expf(scf[i][j] - mq);
                wt[sb + 8 * i][qb + j] = w;
                rs += w;
            }
            rs += __shfl_xor(rs, 1);
            rs += __shfl_xor(rs, 2);
            rs += __shfl_xor(rs, 4);
            if (sb == 0) ts_l[qb + j] = rs;
        }
        __syncthreads();

        // ---- B5: l update ----
        if (tid < 128) l_l[tid] = l_l[tid] * r_l[tid] + ts_l[tid];

        // ---- C: acc rescale + PV accumulation ----
        float rj[8];
        #pragma unroll
        for (int j = 0; j < 8; ++j) rj[j] = r_l[q2 + j];
        #pragma unroll
        for (int j = 0; j < 8; ++j)
            #pragma unroll
            for (int k = 0; k < 8; ++k) acc[j][k] *= rj[j];

        #pragma unroll 4
        for (int s = 0; s < TS; ++s) {
            float4 w0 = *reinterpret_cast<const float4*>(&wt[s][q2]);
            float4 w1 = *reinterpret_cast<const float4*>(&wt[s][q2 + 4]);
            float4 x0 = *reinterpret_cast<const float4*>(&xt[s][c2]);
            float4 x1 = *reinterpret_cast<const float4*>(&xt[s][c2 + 4]);
            float wv[8] = { w0.x, w0.y, w0.z, w0.w, w1.x, w1.y, w1.z, w1.w };
            float xv[8] = { x0.x, x0.y, x0.z, x0.w, x1.x, x1.y, x1.z, x1.w };
            #pragma unroll
            for (int j = 0; j < 8; ++j)
                #pragma unroll
                for (int k = 0; k < 8; ++k)
                    acc[j][k] = fmaf(wv[j], xv[k], acc[j][k]);
        }
    }

    __syncthreads();
    // ---- finalize: write partials ----
    const size_t base = ((size_t)n * SC + scIdx) * 128;
    if (tid < 128) { wsm[base + tid] = m_l[tid]; wsl[base + tid] = l_l[tid]; }
    float* wa = wacc + base * 128;
    #pragma unroll
    for (int j = 0; j < 8; ++j) {
        float4 v0 = make_float4(acc[j][0], acc[j][1], acc[j][2], acc[j][3]);
        float4 v1 = make_float4(acc[j][4], acc[j][5], acc[j][6], acc[j][7]);
        *reinterpret_cast<float4*>(wa + (size_t)(q2 + j) * 128 + c2)     = v0;
        *reinterpret_cast<float4*>(wa + (size_t)(q2 + j) * 128 + c2 + 4) = v1;
    }
}

__global__ __launch_bounds__(128)
void combine(const float* __restrict__ wsm, const float* __restrict__ wsl,
             const float* __restrict__ wacc, float* __restrict__ out, int SC)
{
    const int q = blockIdx.x;
    const int n = blockIdx.y;
    const int t = threadIdx.x;   // c index

    float mstar = -INFINITY;
    for (int sc = 0; sc < SC; ++sc)
        mstar = fmaxf(mstar, wsm[((size_t)n * SC + sc) * 128 + q]);

    float L = 0.f, a = 0.f;
    for (int sc = 0; sc < SC; ++sc) {
        const size_t idx = ((size_t)n * SC + sc) * 128 + q;
        const float e = __expf(wsm[idx] - mstar);
        L += e * wsl[idx];
        a += e * wacc[idx * 128 + t];
    }
    out[((size_t)n * 128 + q) * 128 + t] = a / L;
}

extern "C" void kernel_launch(void* const* d_in, const int* in_sizes, int n_in,
                              void* d_out, int out_size, void* d_ws, size_t ws_size,
                              hipStream_t stream)
{
    (void)in_sizes; (void)n_in; (void)out_size;
    const float* x = (const float*)d_in[0];   // [8,128,36864]
    const float* K = (const float*)d_in[1];   // [8,128,128]
    float* out = (float*)d_out;               // [8,128,128]

    int SC = 64;
    while (SC > 1 && (size_t)8 * SC * (16384 + 256) * sizeof(float) > ws_size) SC >>= 1;
    const int sPerBlock = 36864 / SC;

    float* wsm = (float*)d_ws;
    float* wsl = wsm + (size_t)8 * SC * 128;
    float* wa  = wsl + (size_t)8 * SC * 128;

    flash_partial<<<dim3(SC, 8), 256, 0, stream>>>(x, K, wsm, wsl, wa, SC, sPerBlock);
    combine<<<dim3(128, 8), 128, 0, stream>>>(wsm, wsl, wa, out, SC);
}

// Round 2
// 98.111 us; speedup vs baseline: 3.4020x; 3.4020x over previous
//
#include <hip/hip_runtime.h>
#include <cstdint>

// Attention view: per n (8), queries=K rows (128x128), keys/values = x columns
// (HW=36864 seq, d=128). scores = x^T K^T, softmax over seq, out = softmax^T x^T.
// flash_mfma: split-S online-softmax partials with MFMA (split-bf16 scores).
// combine2: merge partials across s-chunks.

#define C_DIM 128
#define HW_DIM 36864
#define L2E 1.44269504088896340736f

typedef short short8 __attribute__((ext_vector_type(8)));
typedef float f32x16 __attribute__((ext_vector_type(16)));

#if __has_builtin(__builtin_amdgcn_exp2f)
#define EXP2(x) __builtin_amdgcn_exp2f(x)
#else
#define EXP2(x) exp2f(x)
#endif

__device__ __forceinline__ unsigned bf16r(float f) {           // RNE bf16 bits
    unsigned u = __float_as_uint(f);
    return (u + 0x7FFFu + ((u >> 16) & 1u)) >> 16;
}
__device__ __forceinline__ float bf16f(unsigned b) { return __uint_as_float(b << 16); }

// LDS map (bytes):
//   xAhi [64 s][128 c] bf16 swizzled: unit' = (c>>3)^(s&15)     @ 0      (16384)
//   xAlo  same                                                   @ 16384  (16384)
//   xB   [128 c][72 s] bf16 (hi only, pad 72)                    @ 32768  (18432)
//   wls  [128 q][72 s] bf16 (pad 72)                             @ 51200  (18432)
//   epi  [4 qt][128 c][32 q] f32  (union, overlaps the above)    @ 0      (65536)
//   mx/lx [2 sh][4 qt][32 q] f32                                 @ 69632  (2048)

__global__ __launch_bounds__(512, 2)
void flash_mfma(const float* __restrict__ xg, const float* __restrict__ Kg,
                float* __restrict__ wsm, float* __restrict__ wsl,
                float* __restrict__ wacc, int SC, int sPerBlock)
{
    __shared__ char smem[71680];
    unsigned short* xB  = (unsigned short*)(smem + 32768);
    unsigned short* wls = (unsigned short*)(smem + 51200);
    float* epi = (float*)smem;
    float* mx  = (float*)(smem + 69632);
    float* lx  = (float*)(smem + 70656);

    const int tid  = threadIdx.x;
    const int lane = tid & 63;
    const int wv   = tid >> 6;       // wave 0..7
    const int qt   = wv >> 1;        // q-tile 0..3 (32 q each)
    const int sh   = wv & 1;         // s-half 0..1 (32 s each)
    const int l31  = lane & 31;
    const int g    = lane >> 5;

    const int n  = blockIdx.y;
    const int sc = blockIdx.x;
    const size_t xbase = (size_t)n * C_DIM * HW_DIM;

    // ---- K prologue: B-frags (col=q=l31, k=c), hi/lo split, scaled by log2(e) ----
    short8 kh[8], kl[8];
    {
        const float* kp = Kg + ((size_t)n * 128 + 32 * qt + l31) * 128 + g * 8;
        #pragma unroll
        for (int ks = 0; ks < 8; ++ks) {
            float4 a = *(const float4*)(kp + ks * 16);
            float4 b = *(const float4*)(kp + ks * 16 + 4);
            float f[8] = {a.x, a.y, a.z, a.w, b.x, b.y, b.z, b.w};
            short8 h, l;
            #pragma unroll
            for (int j = 0; j < 8; ++j) {
                float v = f[j] * L2E;
                unsigned hb = bf16r(v);
                float rem = v - bf16f(hb);
                h[j] = (short)hb;
                l[j] = (short)bf16r(rem);
            }
            kh[ks] = h; kl[ks] = l;
        }
    }

    // ---- stage mapping: thread owns channel c=tid>>2, s-offsets 4*(tid&3)+16p ----
    const int cS = tid >> 2;
    const int s3 = (tid & 3) << 2;
    const float* xrow = xg + xbase + (size_t)cS * HW_DIM + (size_t)sc * sPerBlock + s3;

    float4 stg[4];
    #pragma unroll
    for (int p = 0; p < 4; ++p) stg[p] = *(const float4*)(xrow + p * 16);

    f32x16 oacc[4];
    #pragma unroll
    for (int ct = 0; ct < 4; ++ct)
        #pragma unroll
        for (int r = 0; r < 16; ++r) oacc[ct][r] = 0.f;
    float m_run = -1e30f, l_run = 0.f;

    const int nT = sPerBlock >> 6;
    for (int t = 0; t < nT; ++t) {
        // ---- convert + write xA (hi/lo, swizzled) and xB ----
        #pragma unroll
        for (int p = 0; p < 4; ++p) {
            float fv[4] = {stg[p].x, stg[p].y, stg[p].z, stg[p].w};
            unsigned hb[4];
            #pragma unroll
            for (int j = 0; j < 4; ++j) {
                int s = 16 * p + s3 + j;
                unsigned h = bf16r(fv[j]);
                hb[j] = h;
                unsigned lo = bf16r(fv[j] - bf16f(h));
                int off = s * 256 + ((((cS >> 3) ^ (s & 15)) << 4)) + (cS & 7) * 2;
                *(unsigned short*)(smem + off) = (unsigned short)h;
                *(unsigned short*)(smem + 16384 + off) = (unsigned short)lo;
            }
            uint2 pk = make_uint2(hb[0] | (hb[1] << 16), hb[2] | (hb[3] << 16));
            *(uint2*)(xB + cS * 72 + 16 * p + s3) = pk;
        }
        // ---- prefetch next tile (overlaps compute, T14) ----
        if (t + 1 < nT) {
            const float* xr = xrow + (size_t)(t + 1) * 64;
            #pragma unroll
            for (int p = 0; p < 4; ++p) stg[p] = *(const float4*)(xr + p * 16);
        }
        __syncthreads();

        // ---- scores: S[s][q] = sum_c x[s][c] * (L2E*K)[q][c], 3-term split ----
        f32x16 sa0, sa1;
        #pragma unroll
        for (int r = 0; r < 16; ++r) { sa0[r] = 0.f; sa1[r] = 0.f; }
        const int srow = 32 * sh + l31;
        #pragma unroll
        for (int ks = 0; ks < 8; ++ks) {
            int off = srow * 256 + (((2 * ks + g) ^ (srow & 15)) << 4);
            short8 xh = *(const short8*)(smem + off);
            short8 xl = *(const short8*)(smem + 16384 + off);
            if (ks & 1) {
                sa1 = __builtin_amdgcn_mfma_f32_32x32x16_bf16(xh, kh[ks], sa1, 0, 0, 0);
                sa1 = __builtin_amdgcn_mfma_f32_32x32x16_bf16(xh, kl[ks], sa1, 0, 0, 0);
                sa1 = __builtin_amdgcn_mfma_f32_32x32x16_bf16(xl, kh[ks], sa1, 0, 0, 0);
            } else {
                sa0 = __builtin_amdgcn_mfma_f32_32x32x16_bf16(xh, kh[ks], sa0, 0, 0, 0);
                sa0 = __builtin_amdgcn_mfma_f32_32x32x16_bf16(xh, kl[ks], sa0, 0, 0, 0);
                sa0 = __builtin_amdgcn_mfma_f32_32x32x16_bf16(xl, kh[ks], sa0, 0, 0, 0);
            }
        }
        float sv[16];
        #pragma unroll
        for (int r = 0; r < 16; ++r) sv[r] = sa0[r] + sa1[r];

        // ---- online softmax (q = l31 per-lane; exp2 domain) ----
        float tm = sv[0];
        #pragma unroll
        for (int r = 1; r < 16; ++r) tm = fmaxf(tm, sv[r]);
        tm = fmaxf(tm, __shfl_xor(tm, 32));
        if (__any(tm > m_run + 11.5f)) {                 // defer-rescale (T13)
            float mnew = fmaxf(m_run, tm);
            float rr = EXP2(m_run - mnew);
            m_run = mnew;
            l_run *= rr;
            #pragma unroll
            for (int ct = 0; ct < 4; ++ct)
                #pragma unroll
                for (int r = 0; r < 16; ++r) oacc[ct][r] *= rr;
        }
        float pw[16];
        float rs = 0.f;
        #pragma unroll
        for (int r = 0; r < 16; ++r) { pw[r] = EXP2(sv[r] - m_run); rs += pw[r]; }
        rs += __shfl_xor(rs, 32);
        l_run += rs;

        // ---- w -> LDS [q][s] (wave-private quadrant; reg r -> s=(r&3)+8(r>>2)+4g) ----
        const int qrow = 32 * qt + l31;
        #pragma unroll
        for (int kk = 0; kk < 4; ++kk) {
            unsigned u0 = bf16r(pw[4 * kk])     | (bf16r(pw[4 * kk + 1]) << 16);
            unsigned u1 = bf16r(pw[4 * kk + 2]) | (bf16r(pw[4 * kk + 3]) << 16);
            int s0 = 8 * kk + 4 * g + 32 * sh;
            *(uint2*)(wls + qrow * 72 + s0) = make_uint2(u0, u1);
        }
        asm volatile("s_waitcnt lgkmcnt(0)" ::: "memory");   // same-wave write->read

        // ---- PV: O^T[c][q] += x[c][s] * w[s][q] ----
        #pragma unroll
        for (int kst = 0; kst < 2; ++kst) {
            int sb = 32 * sh + 16 * kst + g * 8;
            short8 bw = *(const short8*)(wls + (32 * qt + l31) * 72 + sb);
            #pragma unroll
            for (int ct = 0; ct < 4; ++ct) {
                short8 xa = *(const short8*)(xB + (32 * ct + l31) * 72 + sb);
                oacc[ct] = __builtin_amdgcn_mfma_f32_32x32x16_bf16(xa, bw, oacc[ct], 0, 0, 0);
            }
        }
        __syncthreads();
    }

    // ---- epilogue: merge the two s-half waves per q-tile, write partials ----
    if (lane < 32) {
        mx[(sh * 4 + qt) * 32 + lane] = m_run;
        lx[(sh * 4 + qt) * 32 + lane] = l_run;
    }
    __syncthreads();
    float m2 = mx[((sh ^ 1) * 4 + qt) * 32 + l31];
    float l2 = lx[((sh ^ 1) * 4 + qt) * 32 + l31];
    float mStar = fmaxf(m_run, m2);
    float r1 = EXP2(m_run - mStar);
    float lFin = l_run * r1 + l2 * EXP2(m2 - mStar);
    #pragma unroll
    for (int ct = 0; ct < 4; ++ct)
        #pragma unroll
        for (int r = 0; r < 16; ++r) oacc[ct][r] *= r1;
    __syncthreads();                       // epi region (union) now free

    if (sh == 0) {
        #pragma unroll
        for (int ct = 0; ct < 4; ++ct)
            #pragma unroll
            for (int r = 0; r < 16; ++r) {
                int c = 32 * ct + (r & 3) + 8 * (r >> 2) + 4 * g;
                epi[(qt * 128 + c) * 32 + l31] = oacc[ct][r];
            }
    }
    __syncthreads();
    if (sh == 1) {
        const size_t wb = ((size_t)(n * SC + sc)) * 16384;
        #pragma unroll
        for (int ct = 0; ct < 4; ++ct)
            #pragma unroll
            for (int r = 0; r < 16; ++r) {
                int c = 32 * ct + (r & 3) + 8 * (r >> 2) + 4 * g;
                float v = oacc[ct][r] + epi[(qt * 128 + c) * 32 + l31];
                wacc[wb + (size_t)c * 128 + 32 * qt + l31] = v;
            }
        if (lane < 32) {
            wsm[(size_t)(n * SC + sc) * 128 + 32 * qt + lane] = mStar;
            wsl[(size_t)(n * SC + sc) * 128 + 32 * qt + lane] = lFin;
        }
    }
}

__global__ __launch_bounds__(256)
void combine2(const float* __restrict__ wsm, const float* __restrict__ wsl,
              const float* __restrict__ wacc, float* __restrict__ out, int SC)
{
    const int n  = blockIdx.y;
    const int cg = blockIdx.x;           // 16 groups of 8 channels
    const int t  = threadIdx.x;
    const int q  = t & 127;
    const int ch = t >> 7;               // 0..1 -> 4 channels each

    float mm = -1e30f;
    for (int s = 0; s < SC; ++s)
        mm = fmaxf(mm, wsm[(size_t)(n * SC + s) * 128 + q]);

    float L = 0.f, a0 = 0.f, a1 = 0.f, a2 = 0.f, a3 = 0.f;
    for (int s = 0; s < SC; ++s) {
        const size_t b = (size_t)(n * SC + s) * 128;
        float e = EXP2(wsm[b + q] - mm);
        L += e * wsl[b + q];
        const float* wp = wacc + b * 128 + (size_t)(cg * 8 + ch * 4) * 128 + q;
        a0 += e * wp[0];
        a1 += e * wp[128];
        a2 += e * wp[256];
        a3 += e * wp[384];
    }
    float inv = 1.f / L;
    float4 o = make_float4(a0 * inv, a1 * inv, a2 * inv, a3 * inv);
    *(float4*)(&out[((size_t)n * 128 + q) * 128 + cg * 8 + ch * 4]) = o;
}

extern "C" void kernel_launch(void* const* d_in, const int* in_sizes, int n_in,
                              void* d_out, int out_size, void* d_ws, size_t ws_size,
                              hipStream_t stream)
{
    (void)in_sizes; (void)n_in; (void)out_size;
    const float* x = (const float*)d_in[0];   // [8,128,36864]
    const float* K = (const float*)d_in[1];   // [8,128,128]
    float* out = (float*)d_out;               // [8,128,128]

    int SC = 64;
    while (SC > 1 && (size_t)8 * SC * (16384 + 256) * sizeof(float) > ws_size) SC >>= 1;
    const int sPerBlock = HW_DIM / SC;

    float* wsm = (float*)d_ws;
    float* wsl = wsm + (size_t)8 * SC * 128;
    float* wa  = wsl + (size_t)8 * SC * 128;

    flash_mfma<<<dim3(SC, 8), 512, 0, stream>>>(x, K, wsm, wsl, wa, SC, sPerBlock);
    combine2<<<dim3(16, 8), 256, 0, stream>>>(wsm, wsl, wa, out, SC);
}